// Round 6
// baseline (382.184 us; speedup 1.0000x reference)
//
#include <hip/hip_runtime.h>

#define HDIM 128
#define VOCAB 800
#define FB 16
#define NB 32
#define TILE 512
#define TILE_N 256

// ---------- fused: E2 = (emb @ W_f) @ W_s_bot (blocks 0..799), bfs = b_f @ W_s_bot + b_s (block 800)
__global__ void k_prep(const float* __restrict__ emb, const float* __restrict__ W_f,
                       const float* __restrict__ W_s, const float* __restrict__ b_f,
                       const float* __restrict__ b_s, float* __restrict__ E2,
                       float* __restrict__ bfs) {
    __shared__ float e[HDIM], t1[HDIM];
    int j = threadIdx.x;
    int v = blockIdx.x;
    if (v < VOCAB) {
        e[j] = emb[(size_t)v * HDIM + j];
        __syncthreads();
        float a = 0.f;
        for (int k = 0; k < HDIM; ++k)
            a = fmaf(e[k], W_f[k * HDIM + j], a);
        t1[j] = a;
        __syncthreads();
        float b = 0.f;
        for (int k = 0; k < HDIM; ++k)
            b = fmaf(t1[k], W_s[(HDIM + k) * HDIM + j], b);
        E2[(size_t)v * HDIM + j] = b;
    } else {
        e[j] = b_f[j];
        __syncthreads();
        float b = b_s[j];
        for (int k = 0; k < HDIM; ++k)
            b = fmaf(e[k], W_s[(HDIM + k) * HDIM + j], b);
        bfs[j] = b;
    }
}

// ---------- fused: argmax(fragments) [blocks 0..12499] + edge counts [blocks 12500..12890]
__global__ void k_amc(const float* __restrict__ frags, int* __restrict__ frag_id,
                      const int* __restrict__ row, const int* __restrict__ col,
                      int* __restrict__ cntr, int* __restrict__ cntc) {
    int b = blockIdx.x;
    if (b < 12500) {
        int wave = b * 4 + (threadIdx.x >> 6);
        int lane = threadIdx.x & 63;
        const float4* r = reinterpret_cast<const float4*>(frags + (size_t)wave * VOCAB);
        float best = -1e30f;
        int bidx = 0;
        for (int i = lane; i < VOCAB / 4; i += 64) {
            float4 v = r[i];
            int base = i * 4;
            if (v.x > best) { best = v.x; bidx = base + 0; }
            if (v.y > best) { best = v.y; bidx = base + 1; }
            if (v.z > best) { best = v.z; bidx = base + 2; }
            if (v.w > best) { best = v.w; bidx = base + 3; }
        }
        for (int off = 32; off > 0; off >>= 1) {
            float ov = __shfl_xor(best, off, 64);
            int   oi = __shfl_xor(bidx, off, 64);
            if (ov > best || (ov == best && oi < bidx)) { best = ov; bidx = oi; }
        }
        if (lane == 0) frag_id[wave] = bidx;
    } else {
        int i = (b - 12500) * 256 + threadIdx.x;  // over E/4 = 100000 int4s
        if (i < 100000) {
            int4 r4 = reinterpret_cast<const int4*>(row)[i];
            int4 c4 = reinterpret_cast<const int4*>(col)[i];
            atomicAdd(&cntr[r4.x], 1); atomicAdd(&cntr[r4.y], 1);
            atomicAdd(&cntr[r4.z], 1); atomicAdd(&cntr[r4.w], 1);
            atomicAdd(&cntc[c4.x], 1); atomicAdd(&cntc[c4.y], 1);
            atomicAdd(&cntc[c4.z], 1); atomicAdd(&cntc[c4.w], 1);
        }
    }
}

// ---------- per-256-block sums, col then row (fused)
__global__ void k_bsum2(const int* __restrict__ cntc, const int* __restrict__ cntr,
                        int* __restrict__ bsc, int* __restrict__ bsr, int NBC, int F, int N) {
    __shared__ int s[256];
    int t = threadIdx.x;
    const int* cnt;
    int* bsum;
    int bb, L;
    if ((int)blockIdx.x < NBC) { cnt = cntc; bsum = bsc; bb = blockIdx.x; L = F; }
    else                       { cnt = cntr; bsum = bsr; bb = blockIdx.x - NBC; L = N; }
    int i = bb * 256 + t;
    s[t] = (i < L) ? cnt[i] : 0;
    __syncthreads();
    for (int o = 128; o > 0; o >>= 1) {
        if (t < o) s[t] += s[t + o];
        __syncthreads();
    }
    if (t == 0) bsum[bb] = s[0];
}

// ---------- exclusive scan of both block-sum arrays (2 blocks)
__global__ void k_scan2(int* __restrict__ bsc, int* __restrict__ bsr, int nbc, int nbr) {
    __shared__ int s[1024];
    int* bsum = (blockIdx.x == 0) ? bsc : bsr;
    int nb    = (blockIdx.x == 0) ? nbc : nbr;
    int t = threadIdx.x;
    int v = (t < nb) ? bsum[t] : 0;
    s[t] = v;
    __syncthreads();
    for (int o = 1; o < 1024; o <<= 1) {
        int a = (t >= o) ? s[t - o] : 0;
        __syncthreads();
        s[t] += a;
        __syncthreads();
    }
    if (t < nb) bsum[t] = s[t] - v;
}

// ---------- base[i] = bsum[block] + in-block exclusive scan (col + row fused)
__global__ void k_base2(const int* __restrict__ cntc, const int* __restrict__ cntr,
                        const int* __restrict__ bsc, const int* __restrict__ bsr,
                        int* __restrict__ basec, int* __restrict__ baser,
                        int NBC, int F, int N) {
    __shared__ int s[256];
    int t = threadIdx.x;
    const int *cnt, *bsum;
    int* base;
    int bb, L;
    if ((int)blockIdx.x < NBC) { cnt = cntc; bsum = bsc; base = basec; bb = blockIdx.x; L = F; }
    else                       { cnt = cntr; bsum = bsr; base = baser; bb = blockIdx.x - NBC; L = N; }
    int i = bb * 256 + t;
    int v = (i < L) ? cnt[i] : 0;
    s[t] = v;
    __syncthreads();
    for (int o = 1; o < 256; o <<= 1) {
        int a = (t >= o) ? s[t - o] : 0;
        __syncthreads();
        s[t] += a;
        __syncthreads();
    }
    if (i < L) base[i] = bsum[bb] + s[t] - v;
}

// ---------- place edges; cursor IS base (after this, base[i] = orig base[i+1])
__global__ void k_place(const int* __restrict__ row, const int* __restrict__ col,
                        int* __restrict__ basec, int* __restrict__ baser,
                        int* __restrict__ payc, int* __restrict__ payr, int E) {
    int e = blockIdx.x * 256 + threadIdx.x;
    if (e >= E) return;
    int r = row[e], c = col[e];
    int pc = atomicAdd(&basec[c], 1);
    payc[pc] = r;
    int pr = atomicAdd(&baser[r], 1);
    payr[pr] = c;
}

// ---------- fragment pool + matvec; edge-parallel chunks, register run-accum, LDS flush
__global__ __launch_bounds__(256) void k_frag(
        const float* __restrict__ x, const int* __restrict__ basec,
        const int* __restrict__ payc, const int* __restrict__ frag_id,
        const float* __restrict__ W_s, const float* __restrict__ E2,
        const float* __restrict__ bfs, float* __restrict__ femb) {
    __shared__ float s[FB][HDIM];
    __shared__ int eidx[TILE];
    __shared__ int cb[FB + 1];
    int t = threadIdx.x;
    int g = t >> 5, l = t & 31;
    int fb = blockIdx.x * FB;
    if (t <= FB) {
        int idx = fb + t - 1;
        cb[t] = (idx < 0) ? 0 : basec[idx];   // shifted base: start of frag fb+t
    }
    for (int i = t; i < FB * HDIM; i += 256) ((float*)s)[i] = 0.f;
    __syncthreads();
    int p0 = cb[0], pend = cb[FB];
    const float4* x4 = reinterpret_cast<const float4*>(x);
    for (int tb = p0; tb < pend; tb += TILE) {
        int nload = min(TILE, pend - tb);
        for (int i = t; i < nload; i += 256) eidx[i] = payc[tb + i];
        __syncthreads();
        int ck = (nload + 7) >> 3;
        int beg = g * ck, end = min(beg + ck, nload);
        if (beg < end) {
            int cur = 0;
            while (tb + beg >= cb[cur + 1]) ++cur;
            float4 acc = make_float4(0.f, 0.f, 0.f, 0.f);
            for (int p = beg; p < end; p += 4) {
                int n4 = min(4, end - p);
                float4 v0, v1, v2, v3;
                v0 = x4[(size_t)eidx[p] * 32 + l];
                if (n4 > 1) v1 = x4[(size_t)eidx[p + 1] * 32 + l];
                if (n4 > 2) v2 = x4[(size_t)eidx[p + 2] * 32 + l];
                if (n4 > 3) v3 = x4[(size_t)eidx[p + 3] * 32 + l];
#pragma unroll
                for (int k = 0; k < 4; ++k) {
                    if (k >= n4) break;
                    int gp = tb + p + k;
                    if (gp >= cb[cur + 1]) {
                        atomicAdd(&s[cur][l * 4 + 0], acc.x);
                        atomicAdd(&s[cur][l * 4 + 1], acc.y);
                        atomicAdd(&s[cur][l * 4 + 2], acc.z);
                        atomicAdd(&s[cur][l * 4 + 3], acc.w);
                        acc = make_float4(0.f, 0.f, 0.f, 0.f);
                        do { ++cur; } while (gp >= cb[cur + 1]);
                    }
                    float4 v = (k == 0) ? v0 : (k == 1) ? v1 : (k == 2) ? v2 : v3;
                    acc.x += v.x; acc.y += v.y; acc.z += v.z; acc.w += v.w;
                }
            }
            atomicAdd(&s[cur][l * 4 + 0], acc.x);
            atomicAdd(&s[cur][l * 4 + 1], acc.y);
            atomicAdd(&s[cur][l * 4 + 2], acc.z);
            atomicAdd(&s[cur][l * 4 + 3], acc.w);
        }
        __syncthreads();
    }
    // normalize to mean
    for (int i = t; i < FB * HDIM; i += 256) {
        int f = i >> 7;
        int dg = cb[f + 1] - cb[f];
        ((float*)s)[i] *= 1.0f / fmaxf((float)dg, 1.0f);
    }
    __syncthreads();
    // matvec: thread = dim d, 8 fragments per half-block
    int d = t & 127;
    int fh = t >> 7;
    float bv = bfs[d];
    float acc[8];
#pragma unroll
    for (int f = 0; f < 8; ++f)
        acc[f] = E2[(size_t)frag_id[fb + fh * 8 + f] * HDIM + d] + bv;
    for (int k = 0; k < HDIM; k += 4) {
        float w0 = W_s[(k + 0) * HDIM + d];
        float w1 = W_s[(k + 1) * HDIM + d];
        float w2 = W_s[(k + 2) * HDIM + d];
        float w3 = W_s[(k + 3) * HDIM + d];
#pragma unroll
        for (int f = 0; f < 8; ++f) {
            const float4 sv = *reinterpret_cast<const float4*>(&s[fh * 8 + f][k]);
            acc[f] = fmaf(sv.x, w0, acc[f]);
            acc[f] = fmaf(sv.y, w1, acc[f]);
            acc[f] = fmaf(sv.z, w2, acc[f]);
            acc[f] = fmaf(sv.w, w3, acc[f]);
        }
    }
#pragma unroll
    for (int f = 0; f < 8; ++f)
        femb[(size_t)(fb + fh * 8 + f) * HDIM + d] = acc[f];
}

// ---------- node pool + divide; edge-parallel chunks, register run-accum, LDS flush
__global__ __launch_bounds__(256) void k_node(
        const float* __restrict__ femb, const int* __restrict__ baser,
        const int* __restrict__ payr, float* __restrict__ out, int N) {
    __shared__ float s[NB][HDIM];
    __shared__ int eidx[TILE_N];
    __shared__ int cb[NB + 1];
    int t = threadIdx.x;
    int g = t >> 5, l = t & 31;
    int n0 = blockIdx.x * NB;
    if (t <= NB) {
        int idx = n0 + t - 1;
        cb[t] = (idx < 0) ? 0 : baser[idx];   // shifted base: start of node n0+t
    }
    for (int i = t; i < NB * HDIM; i += 256) ((float*)s)[i] = 0.f;
    __syncthreads();
    int p0 = cb[0], pend = cb[NB];
    const float4* f4p = reinterpret_cast<const float4*>(femb);
    for (int tb = p0; tb < pend; tb += TILE_N) {
        int nload = min(TILE_N, pend - tb);
        for (int i = t; i < nload; i += 256) eidx[i] = payr[tb + i];
        __syncthreads();
        int ck = (nload + 7) >> 3;
        int beg = g * ck, end = min(beg + ck, nload);
        if (beg < end) {
            int cur = 0;
            while (tb + beg >= cb[cur + 1]) ++cur;
            float4 acc = make_float4(0.f, 0.f, 0.f, 0.f);
            for (int p = beg; p < end; p += 4) {
                int n4 = min(4, end - p);
                float4 v0, v1, v2, v3;
                v0 = f4p[(size_t)eidx[p] * 32 + l];
                if (n4 > 1) v1 = f4p[(size_t)eidx[p + 1] * 32 + l];
                if (n4 > 2) v2 = f4p[(size_t)eidx[p + 2] * 32 + l];
                if (n4 > 3) v3 = f4p[(size_t)eidx[p + 3] * 32 + l];
#pragma unroll
                for (int k = 0; k < 4; ++k) {
                    if (k >= n4) break;
                    int gp = tb + p + k;
                    if (gp >= cb[cur + 1]) {
                        atomicAdd(&s[cur][l * 4 + 0], acc.x);
                        atomicAdd(&s[cur][l * 4 + 1], acc.y);
                        atomicAdd(&s[cur][l * 4 + 2], acc.z);
                        atomicAdd(&s[cur][l * 4 + 3], acc.w);
                        acc = make_float4(0.f, 0.f, 0.f, 0.f);
                        do { ++cur; } while (gp >= cb[cur + 1]);
                    }
                    float4 v = (k == 0) ? v0 : (k == 1) ? v1 : (k == 2) ? v2 : v3;
                    acc.x += v.x; acc.y += v.y; acc.z += v.z; acc.w += v.w;
                }
            }
            atomicAdd(&s[cur][l * 4 + 0], acc.x);
            atomicAdd(&s[cur][l * 4 + 1], acc.y);
            atomicAdd(&s[cur][l * 4 + 2], acc.z);
            atomicAdd(&s[cur][l * 4 + 3], acc.w);
        }
        __syncthreads();
    }
    // mean + write out
    float4* o4 = reinterpret_cast<float4*>(out);
    for (int i = t; i < NB * 32; i += 256) {
        int r = i >> 5, c4 = i & 31;
        int dg = cb[r + 1] - cb[r];
        float inv = 1.0f / fmaxf((float)dg, 1.0f);
        float4 v = *reinterpret_cast<const float4*>(&s[r][c4 * 4]);
        v.x *= inv; v.y *= inv; v.z *= inv; v.w *= inv;
        o4[(size_t)(n0 + r) * 32 + c4] = v;
    }
}

extern "C" void kernel_launch(void* const* d_in, const int* in_sizes, int n_in,
                              void* d_out, int out_size, void* d_ws, size_t ws_size,
                              hipStream_t stream) {
    const float* x         = (const float*)d_in[0];
    const float* fragments = (const float*)d_in[1];
    const float* emb_table = (const float*)d_in[2];
    const float* W_f       = (const float*)d_in[3];
    const float* b_f       = (const float*)d_in[4];
    const float* W_s       = (const float*)d_in[5];
    const float* b_s       = (const float*)d_in[6];
    const int*   row       = (const int*)d_in[7];
    const int*   col       = (const int*)d_in[8];
    float* out = (float*)d_out;

    const int N = 200000, F = 50000, E = 400000;
    const int NBC = (F + 255) / 256;   // 196
    const int NBR = (N + 255) / 256;   // 782

    float* femb  = (float*)d_ws;                     // F*128
    int* cntc    = (int*)(femb + (size_t)F * HDIM);  // F
    int* cntr    = cntc + F;                         // N
    int* basec   = cntr + N;                         // F
    int* baser   = basec + F;                        // N
    int* bsc     = baser + N;                        // 1024
    int* bsr     = bsc + 1024;                       // 1024
    int* payc    = bsr + 1024;                       // E
    int* payr    = payc + E;                         // E
    int* frag_id = payr + E;                         // F
    float* E2    = (float*)(frag_id + F);            // VOCAB*128
    float* bfs   = E2 + VOCAB * HDIM;                // 128

    hipMemsetAsync(cntc, 0, (size_t)(F + N) * sizeof(int), stream);

    k_amc<<<12500 + 391, 256, 0, stream>>>(fragments, frag_id, row, col, cntr, cntc);
    k_bsum2<<<NBC + NBR, 256, 0, stream>>>(cntc, cntr, bsc, bsr, NBC, F, N);
    k_scan2<<<2, 1024, 0, stream>>>(bsc, bsr, NBC, NBR);
    k_base2<<<NBC + NBR, 256, 0, stream>>>(cntc, cntr, bsc, bsr, basec, baser, NBC, F, N);
    k_place<<<(E + 255) / 256, 256, 0, stream>>>(row, col, basec, baser, payc, payr, E);
    k_prep<<<VOCAB + 1, HDIM, 0, stream>>>(emb_table, W_f, W_s, b_f, b_s, E2, bfs);
    k_frag<<<F / FB, 256, 0, stream>>>(x, basec, payc, frag_id, W_s, E2, bfs, femb);
    k_node<<<N / NB, 256, 0, stream>>>(femb, baser, payr, out, N);
}

// Round 7
// 250.971 us; speedup vs baseline: 1.5228x; 1.5228x over previous
//
#include <hip/hip_runtime.h>

#define HDIM 128
#define VOCAB 800
#define FB 16
#define NB 64
#define TILE 1024
#define TILE_N 512

typedef float f4 __attribute__((ext_vector_type(4)));

#define ACCB(a, h) { \
    a.x += __uint_as_float(h.x << 16); \
    a.y += __uint_as_float(h.x & 0xffff0000u); \
    a.z += __uint_as_float(h.y << 16); \
    a.w += __uint_as_float(h.y & 0xffff0000u); }

static __device__ __forceinline__ unsigned short f2bf(float f) {
    unsigned int u = __float_as_uint(f);
    return (unsigned short)((u + 0x7fffu + ((u >> 16) & 1u)) >> 16);
}

// ---------- fused: E2 = (emb @ W_f) @ W_s_bot (blocks 0..799), bfs = b_f @ W_s_bot + b_s (block 800)
__global__ void k_prep(const float* __restrict__ emb, const float* __restrict__ W_f,
                       const float* __restrict__ W_s, const float* __restrict__ b_f,
                       const float* __restrict__ b_s, float* __restrict__ E2,
                       float* __restrict__ bfs) {
    __shared__ float e[HDIM], t1[HDIM];
    int j = threadIdx.x;
    int v = blockIdx.x;
    if (v < VOCAB) {
        e[j] = emb[(size_t)v * HDIM + j];
        __syncthreads();
        float a = 0.f;
        for (int k = 0; k < HDIM; ++k)
            a = fmaf(e[k], W_f[k * HDIM + j], a);
        t1[j] = a;
        __syncthreads();
        float b = 0.f;
        for (int k = 0; k < HDIM; ++k)
            b = fmaf(t1[k], W_s[(HDIM + k) * HDIM + j], b);
        E2[(size_t)v * HDIM + j] = b;
    } else {
        e[j] = b_f[j];
        __syncthreads();
        float b = b_s[j];
        for (int k = 0; k < HDIM; ++k)
            b = fmaf(e[k], W_s[(HDIM + k) * HDIM + j], b);
        bfs[j] = b;
    }
}

// ---------- fused streaming kernel:
// blocks [0,12500): argmax(fragments) via nt loads
// blocks [12500,12891): edge degree counts
// blocks [12891,25391): x -> bf16 xb (nt loads of x, normal stores of xb -> stays in L3)
__global__ void k_amc(const float* __restrict__ frags, int* __restrict__ frag_id,
                      const float* __restrict__ x, unsigned short* __restrict__ xb,
                      const int* __restrict__ row, const int* __restrict__ col,
                      int* __restrict__ cntr, int* __restrict__ cntc) {
    int b = blockIdx.x, t = threadIdx.x;
    if (b < 12500) {
        int wave = b * 4 + (t >> 6);
        int lane = t & 63;
        const f4* r = reinterpret_cast<const f4*>(frags + (size_t)wave * VOCAB);
        float best = -1e30f;
        int bidx = 0;
        for (int i = lane; i < VOCAB / 4; i += 64) {
            f4 v = __builtin_nontemporal_load(r + i);
            int base = i * 4;
            if (v.x > best) { best = v.x; bidx = base + 0; }
            if (v.y > best) { best = v.y; bidx = base + 1; }
            if (v.z > best) { best = v.z; bidx = base + 2; }
            if (v.w > best) { best = v.w; bidx = base + 3; }
        }
        for (int off = 32; off > 0; off >>= 1) {
            float ov = __shfl_xor(best, off, 64);
            int   oi = __shfl_xor(bidx, off, 64);
            if (ov > best || (ov == best && oi < bidx)) { best = ov; bidx = oi; }
        }
        if (lane == 0) frag_id[wave] = bidx;
    } else if (b < 12891) {
        int i = (b - 12500) * 256 + t;  // over E/4 = 100000 int4s
        if (i < 100000) {
            int4 r4 = reinterpret_cast<const int4*>(row)[i];
            int4 c4 = reinterpret_cast<const int4*>(col)[i];
            atomicAdd(&cntr[r4.x], 1); atomicAdd(&cntr[r4.y], 1);
            atomicAdd(&cntr[r4.z], 1); atomicAdd(&cntr[r4.w], 1);
            atomicAdd(&cntc[c4.x], 1); atomicAdd(&cntc[c4.y], 1);
            atomicAdd(&cntc[c4.z], 1); atomicAdd(&cntc[c4.w], 1);
        }
    } else {
        size_t i = (size_t)(b - 12891) * 256 + t;   // 12500*256 threads, 8 floats each
        const f4* xp = reinterpret_cast<const f4*>(x);
        f4 v0 = __builtin_nontemporal_load(xp + 2 * i);
        f4 v1 = __builtin_nontemporal_load(xp + 2 * i + 1);
        uint4 o;
        o.x = (unsigned)f2bf(v0.x) | ((unsigned)f2bf(v0.y) << 16);
        o.y = (unsigned)f2bf(v0.z) | ((unsigned)f2bf(v0.w) << 16);
        o.z = (unsigned)f2bf(v1.x) | ((unsigned)f2bf(v1.y) << 16);
        o.w = (unsigned)f2bf(v1.z) | ((unsigned)f2bf(v1.w) << 16);
        *reinterpret_cast<uint4*>(xb + i * 8) = o;
    }
}

// ---------- per-256-block sums, col then row (fused)
__global__ void k_bsum2(const int* __restrict__ cntc, const int* __restrict__ cntr,
                        int* __restrict__ bsc, int* __restrict__ bsr, int NBC, int F, int N) {
    __shared__ int s[256];
    int t = threadIdx.x;
    const int* cnt;
    int* bsum;
    int bb, L;
    if ((int)blockIdx.x < NBC) { cnt = cntc; bsum = bsc; bb = blockIdx.x; L = F; }
    else                       { cnt = cntr; bsum = bsr; bb = blockIdx.x - NBC; L = N; }
    int i = bb * 256 + t;
    s[t] = (i < L) ? cnt[i] : 0;
    __syncthreads();
    for (int o = 128; o > 0; o >>= 1) {
        if (t < o) s[t] += s[t + o];
        __syncthreads();
    }
    if (t == 0) bsum[bb] = s[0];
}

// ---------- exclusive scan of both block-sum arrays (2 blocks)
__global__ void k_scan2(int* __restrict__ bsc, int* __restrict__ bsr, int nbc, int nbr) {
    __shared__ int s[1024];
    int* bsum = (blockIdx.x == 0) ? bsc : bsr;
    int nb    = (blockIdx.x == 0) ? nbc : nbr;
    int t = threadIdx.x;
    int v = (t < nb) ? bsum[t] : 0;
    s[t] = v;
    __syncthreads();
    for (int o = 1; o < 1024; o <<= 1) {
        int a = (t >= o) ? s[t - o] : 0;
        __syncthreads();
        s[t] += a;
        __syncthreads();
    }
    if (t < nb) bsum[t] = s[t] - v;
}

// ---------- base[i] = bsum[block] + in-block exclusive scan (col + row fused)
__global__ void k_base2(const int* __restrict__ cntc, const int* __restrict__ cntr,
                        const int* __restrict__ bsc, const int* __restrict__ bsr,
                        int* __restrict__ basec, int* __restrict__ baser,
                        int NBC, int F, int N) {
    __shared__ int s[256];
    int t = threadIdx.x;
    const int *cnt, *bsum;
    int* base;
    int bb, L;
    if ((int)blockIdx.x < NBC) { cnt = cntc; bsum = bsc; base = basec; bb = blockIdx.x; L = F; }
    else                       { cnt = cntr; bsum = bsr; base = baser; bb = blockIdx.x - NBC; L = N; }
    int i = bb * 256 + t;
    int v = (i < L) ? cnt[i] : 0;
    s[t] = v;
    __syncthreads();
    for (int o = 1; o < 256; o <<= 1) {
        int a = (t >= o) ? s[t - o] : 0;
        __syncthreads();
        s[t] += a;
        __syncthreads();
    }
    if (i < L) base[i] = bsum[bb] + s[t] - v;
}

// ---------- place edges; cursor IS base (after this, base[i] = orig start of i+1)
__global__ void k_place(const int* __restrict__ row, const int* __restrict__ col,
                        int* __restrict__ basec, int* __restrict__ baser,
                        int* __restrict__ payc, int* __restrict__ payr, int E) {
    int e = blockIdx.x * 256 + threadIdx.x;
    if (e >= E) return;
    int r = row[e], c = col[e];
    int pc = atomicAdd(&basec[c], 1);
    payc[pc] = r;
    int pr = atomicAdd(&baser[r], 1);
    payr[pr] = c;
}

// ---------- fragment pool (bf16 xb gather, L3-resident) + matvec; writes bf16 femb
__global__ __launch_bounds__(256) void k_frag(
        const unsigned short* __restrict__ xb, const int* __restrict__ basec,
        const int* __restrict__ payc, const int* __restrict__ frag_id,
        const float* __restrict__ W_s, const float* __restrict__ E2,
        const float* __restrict__ bfs, unsigned short* __restrict__ fembb) {
    __shared__ float s[FB][HDIM];
    __shared__ int eidx[TILE];
    __shared__ int cb[FB + 1];
    int t = threadIdx.x;
    int g = t >> 5, l = t & 31;
    int fb = blockIdx.x * FB;
    if (t <= FB) {
        int idx = fb + t - 1;
        cb[t] = (idx < 0) ? 0 : basec[idx];   // shifted base: start of frag fb+t
    }
    __syncthreads();
    int st0 = cb[g],     d0 = cb[g + 1] - cb[g];
    int st1 = cb[8 + g], d1 = cb[9 + g] - cb[8 + g];
    int p0 = cb[0], pend = cb[FB];
    const uint2* x2 = reinterpret_cast<const uint2*>(xb);
    float4 a0A = make_float4(0.f, 0.f, 0.f, 0.f), a0B = a0A, a1A = a0A, a1B = a0A;
    for (int tb = p0; tb < pend; tb += TILE) {
        int nload = min(TILE, pend - tb);
        for (int i = t; i < nload; i += 256) eidx[i] = payc[tb + i];
        __syncthreads();
        int lim = tb + nload;
        int lo0 = max(st0, tb) - tb, hi0 = min(st0 + d0, lim) - tb;
        int lo1 = max(st1, tb) - tb, hi1 = min(st1 + d1, lim) - tb;
        int m = max(hi0 - lo0, hi1 - lo1);
        for (int j = 0; j < m; j += 2) {
            if (lo0 + j < hi0)     { uint2 h = x2[(size_t)eidx[lo0 + j]     * 32 + l]; ACCB(a0A, h); }
            if (lo0 + j + 1 < hi0) { uint2 h = x2[(size_t)eidx[lo0 + j + 1] * 32 + l]; ACCB(a0B, h); }
            if (lo1 + j < hi1)     { uint2 h = x2[(size_t)eidx[lo1 + j]     * 32 + l]; ACCB(a1A, h); }
            if (lo1 + j + 1 < hi1) { uint2 h = x2[(size_t)eidx[lo1 + j + 1] * 32 + l]; ACCB(a1B, h); }
        }
        __syncthreads();
    }
    float inv0 = 1.0f / fmaxf((float)d0, 1.0f);
    float inv1 = 1.0f / fmaxf((float)d1, 1.0f);
    float4 r0, r1;
    r0.x = (a0A.x + a0B.x) * inv0; r0.y = (a0A.y + a0B.y) * inv0;
    r0.z = (a0A.z + a0B.z) * inv0; r0.w = (a0A.w + a0B.w) * inv0;
    r1.x = (a1A.x + a1B.x) * inv1; r1.y = (a1A.y + a1B.y) * inv1;
    r1.z = (a1A.z + a1B.z) * inv1; r1.w = (a1A.w + a1B.w) * inv1;
    *reinterpret_cast<float4*>(&s[g][l * 4]) = r0;
    *reinterpret_cast<float4*>(&s[8 + g][l * 4]) = r1;
    __syncthreads();
    // matvec: thread = dim d, 8 fragments per half-block
    int d = t & 127;
    int fh = t >> 7;
    float bv = bfs[d];
    float acc[8];
#pragma unroll
    for (int f = 0; f < 8; ++f)
        acc[f] = E2[(size_t)frag_id[fb + fh * 8 + f] * HDIM + d] + bv;
    for (int k = 0; k < HDIM; k += 4) {
        float w0 = W_s[(k + 0) * HDIM + d];
        float w1 = W_s[(k + 1) * HDIM + d];
        float w2 = W_s[(k + 2) * HDIM + d];
        float w3 = W_s[(k + 3) * HDIM + d];
#pragma unroll
        for (int f = 0; f < 8; ++f) {
            const float4 sv = *reinterpret_cast<const float4*>(&s[fh * 8 + f][k]);
            acc[f] = fmaf(sv.x, w0, acc[f]);
            acc[f] = fmaf(sv.y, w1, acc[f]);
            acc[f] = fmaf(sv.z, w2, acc[f]);
            acc[f] = fmaf(sv.w, w3, acc[f]);
        }
    }
#pragma unroll
    for (int f = 0; f < 8; ++f)
        fembb[(size_t)(fb + fh * 8 + f) * HDIM + d] = f2bf(acc[f]);
}

// ---------- node pool + divide; bf16 femb gather (L3-resident), nt out stores
__global__ __launch_bounds__(256) void k_node(
        const unsigned short* __restrict__ fembb, const int* __restrict__ baser,
        const int* __restrict__ payr, float* __restrict__ out, int N) {
    __shared__ int eidx[TILE_N];
    __shared__ int cb[NB + 1];
    int t = threadIdx.x;
    int g = t >> 5, l = t & 31;
    int n0 = blockIdx.x * NB;
    if (t <= NB) {
        int idx = n0 + t - 1;
        cb[t] = (idx < 0) ? 0 : baser[idx];   // shifted base: start of node n0+t
    }
    __syncthreads();
    int st_[8], dg_[8];
    float4 a[8];
#pragma unroll
    for (int i = 0; i < 8; ++i) {
        st_[i] = cb[g * 8 + i];
        dg_[i] = cb[g * 8 + i + 1] - st_[i];
        a[i] = make_float4(0.f, 0.f, 0.f, 0.f);
    }
    int p0 = cb[0], pend = cb[NB];
    const uint2* f2p = reinterpret_cast<const uint2*>(fembb);
    for (int tb = p0; tb < pend; tb += TILE_N) {
        int nload = min(TILE_N, pend - tb);
        for (int i = t; i < nload; i += 256) eidx[i] = payr[tb + i];
        __syncthreads();
        int lim = tb + nload;
        int lo[8], hi[8];
        int m = 0;
#pragma unroll
        for (int i = 0; i < 8; ++i) {
            lo[i] = max(st_[i], tb) - tb;
            hi[i] = min(st_[i] + dg_[i], lim) - tb;
            m = max(m, hi[i] - lo[i]);
        }
        for (int j = 0; j < m; ++j) {
#pragma unroll
            for (int i = 0; i < 8; ++i) {
                if (lo[i] + j < hi[i]) {
                    uint2 h = f2p[(size_t)eidx[lo[i] + j] * 32 + l];
                    ACCB(a[i], h);
                }
            }
        }
        __syncthreads();
    }
    f4* o4 = reinterpret_cast<f4*>(out);
#pragma unroll
    for (int i = 0; i < 8; ++i) {
        float inv = 1.0f / fmaxf((float)dg_[i], 1.0f);
        f4 v;
        v.x = a[i].x * inv; v.y = a[i].y * inv;
        v.z = a[i].z * inv; v.w = a[i].w * inv;
        __builtin_nontemporal_store(v, o4 + (size_t)(n0 + g * 8 + i) * 32 + l);
    }
}

extern "C" void kernel_launch(void* const* d_in, const int* in_sizes, int n_in,
                              void* d_out, int out_size, void* d_ws, size_t ws_size,
                              hipStream_t stream) {
    const float* x         = (const float*)d_in[0];
    const float* fragments = (const float*)d_in[1];
    const float* emb_table = (const float*)d_in[2];
    const float* W_f       = (const float*)d_in[3];
    const float* b_f       = (const float*)d_in[4];
    const float* W_s       = (const float*)d_in[5];
    const float* b_s       = (const float*)d_in[6];
    const int*   row       = (const int*)d_in[7];
    const int*   col       = (const int*)d_in[8];
    float* out = (float*)d_out;

    const int N = 200000, F = 50000, E = 400000;
    const int NBC = (F + 255) / 256;   // 196
    const int NBR = (N + 255) / 256;   // 782

    // xb (bf16 x, 51.2 MB) lives in d_out: fully dead before k_node overwrites out.
    unsigned short* xb = (unsigned short*)d_out;

    unsigned short* fembb = (unsigned short*)d_ws;     // F*128 bf16 = 12.8 MB
    int* cntc    = (int*)(fembb + (size_t)F * HDIM);   // F
    int* cntr    = cntc + F;                           // N
    int* basec   = cntr + N;                           // F
    int* baser   = basec + F;                          // N
    int* bsc     = baser + N;                          // 1024
    int* bsr     = bsc + 1024;                         // 1024
    int* payc    = bsr + 1024;                         // E
    int* payr    = payc + E;                           // E
    int* frag_id = payr + E;                           // F
    float* E2    = (float*)(frag_id + F);              // VOCAB*128
    float* bfs   = E2 + VOCAB * HDIM;                  // 128

    hipMemsetAsync(cntc, 0, (size_t)(F + N) * sizeof(int), stream);

    k_amc<<<12891 + 12500, 256, 0, stream>>>(fragments, frag_id, x, xb, row, col, cntr, cntc);
    k_bsum2<<<NBC + NBR, 256, 0, stream>>>(cntc, cntr, bsc, bsr, NBC, F, N);
    k_scan2<<<2, 1024, 0, stream>>>(bsc, bsr, NBC, NBR);
    k_base2<<<NBC + NBR, 256, 0, stream>>>(cntc, cntr, bsc, bsr, basec, baser, NBC, F, N);
    k_place<<<(E + 255) / 256, 256, 0, stream>>>(row, col, basec, baser, payc, payr, E);
    k_prep<<<VOCAB + 1, HDIM, 0, stream>>>(emb_table, W_f, W_s, b_f, b_s, E2, bfs);
    k_frag<<<F / FB, 256, 0, stream>>>(xb, basec, payc, frag_id, W_s, E2, bfs, fembb);
    k_node<<<N / NB, 256, 0, stream>>>(fembb, baser, payr, out, N);
}

// Round 8
// 250.074 us; speedup vs baseline: 1.5283x; 1.0036x over previous
//
#include <hip/hip_runtime.h>

#define HDIM 128
#define VOCAB 800
#define FB 32
#define NB 64
#define TILE 1024
#define TILE_N 512

typedef float f4 __attribute__((ext_vector_type(4)));
typedef float f2 __attribute__((ext_vector_type(2)));

#define ACCB(a, h) { \
    a.x += __uint_as_float(h.x << 16); \
    a.y += __uint_as_float(h.x & 0xffff0000u); \
    a.z += __uint_as_float(h.y << 16); \
    a.w += __uint_as_float(h.y & 0xffff0000u); }

static __device__ __forceinline__ unsigned short f2bf(float f) {
    unsigned int u = __float_as_uint(f);
    return (unsigned short)((u + 0x7fffu + ((u >> 16) & 1u)) >> 16);
}

// ---------- mega streaming kernel:
// [0,12500)       argmax(fragments) via nt loads
// [12500,12891)   edge degree counts into concatenated cnt[] (cols at 0, rows at F)
// [12891,25391)   x -> bf16 xb (nt loads)
// [25391,25792)   E2 = (emb @ W_f) @ W_s_bot ; bfs = b_f @ W_s_bot + b_s
__global__ void k_amc(const float* __restrict__ frags, int* __restrict__ frag_id,
                      const float* __restrict__ x, unsigned short* __restrict__ xb,
                      const int* __restrict__ row, const int* __restrict__ col,
                      int* __restrict__ cnt,
                      const float* __restrict__ emb, const float* __restrict__ W_f,
                      const float* __restrict__ W_s, const float* __restrict__ b_f,
                      const float* __restrict__ b_s, float* __restrict__ E2,
                      float* __restrict__ bfs, int F) {
    __shared__ float e[2][HDIM], t1[2][HDIM];
    int b = blockIdx.x, t = threadIdx.x;
    if (b < 12500) {
        int wave = b * 4 + (t >> 6);
        int lane = t & 63;
        const f4* r = reinterpret_cast<const f4*>(frags + (size_t)wave * VOCAB);
        float best = -1e30f;
        int bidx = 0;
        for (int i = lane; i < VOCAB / 4; i += 64) {
            f4 v = __builtin_nontemporal_load(r + i);
            int base = i * 4;
            if (v.x > best) { best = v.x; bidx = base + 0; }
            if (v.y > best) { best = v.y; bidx = base + 1; }
            if (v.z > best) { best = v.z; bidx = base + 2; }
            if (v.w > best) { best = v.w; bidx = base + 3; }
        }
        for (int off = 32; off > 0; off >>= 1) {
            float ov = __shfl_xor(best, off, 64);
            int   oi = __shfl_xor(bidx, off, 64);
            if (ov > best || (ov == best && oi < bidx)) { best = ov; bidx = oi; }
        }
        if (lane == 0) frag_id[wave] = bidx;
    } else if (b < 12891) {
        int i = (b - 12500) * 256 + t;  // over E/4 = 100000 int4s
        if (i < 100000) {
            int4 r4 = reinterpret_cast<const int4*>(row)[i];
            int4 c4 = reinterpret_cast<const int4*>(col)[i];
            atomicAdd(&cnt[F + r4.x], 1); atomicAdd(&cnt[F + r4.y], 1);
            atomicAdd(&cnt[F + r4.z], 1); atomicAdd(&cnt[F + r4.w], 1);
            atomicAdd(&cnt[c4.x], 1); atomicAdd(&cnt[c4.y], 1);
            atomicAdd(&cnt[c4.z], 1); atomicAdd(&cnt[c4.w], 1);
        }
    } else if (b < 25391) {
        size_t i = (size_t)(b - 12891) * 256 + t;
        const f4* xp = reinterpret_cast<const f4*>(x);
        f4 v0 = __builtin_nontemporal_load(xp + 2 * i);
        f4 v1 = __builtin_nontemporal_load(xp + 2 * i + 1);
        uint4 o;
        o.x = (unsigned)f2bf(v0.x) | ((unsigned)f2bf(v0.y) << 16);
        o.y = (unsigned)f2bf(v0.z) | ((unsigned)f2bf(v0.w) << 16);
        o.z = (unsigned)f2bf(v1.x) | ((unsigned)f2bf(v1.y) << 16);
        o.w = (unsigned)f2bf(v1.z) | ((unsigned)f2bf(v1.w) << 16);
        *reinterpret_cast<uint4*>(xb + i * 8) = o;
    } else {
        int bp = b - 25391;         // 0..400
        int j = t & 127, half = t >> 7;
        if (bp < 400) {
            int v = bp * 2 + half;
            e[half][j] = emb[(size_t)v * HDIM + j];
            __syncthreads();
            float a = 0.f;
            for (int k = 0; k < HDIM; ++k)
                a = fmaf(e[half][k], W_f[k * HDIM + j], a);
            t1[half][j] = a;
            __syncthreads();
            float bb = 0.f;
            for (int k = 0; k < HDIM; ++k)
                bb = fmaf(t1[half][k], W_s[(HDIM + k) * HDIM + j], bb);
            E2[(size_t)v * HDIM + j] = bb;
        } else {
            if (half == 0) e[0][j] = b_f[j];
            __syncthreads();
            if (half == 0) {
                float bb = b_s[j];
                for (int k = 0; k < HDIM; ++k)
                    bb = fmaf(e[0][k], W_s[(HDIM + k) * HDIM + j], bb);
                bfs[j] = bb;
            }
        }
    }
}

// ---------- per-256-block sums over concatenated cnt (L = F+N)
__global__ void k_bsum(const int* __restrict__ cnt, int L, int* __restrict__ bsum) {
    __shared__ int s[256];
    int t = threadIdx.x;
    int i = blockIdx.x * 256 + t;
    s[t] = (i < L) ? cnt[i] : 0;
    __syncthreads();
    for (int o = 128; o > 0; o >>= 1) {
        if (t < o) s[t] += s[t + o];
        __syncthreads();
    }
    if (t == 0) bsum[blockIdx.x] = s[0];
}

// ---------- exclusive scan of block sums (nb <= 1024), single block
__global__ void k_scan(int* __restrict__ bsum, int nb) {
    __shared__ int s[1024];
    int t = threadIdx.x;
    int v = (t < nb) ? bsum[t] : 0;
    s[t] = v;
    __syncthreads();
    for (int o = 1; o < 1024; o <<= 1) {
        int a = (t >= o) ? s[t - o] : 0;
        __syncthreads();
        s[t] += a;
        __syncthreads();
    }
    if (t < nb) bsum[t] = s[t] - v;
}

// ---------- base[i] = bsum[block] + in-block exclusive scan
__global__ void k_base(const int* __restrict__ cnt, const int* __restrict__ bsum, int L,
                       int* __restrict__ base) {
    __shared__ int s[256];
    int t = threadIdx.x;
    int i = blockIdx.x * 256 + t;
    int v = (i < L) ? cnt[i] : 0;
    s[t] = v;
    __syncthreads();
    for (int o = 1; o < 256; o <<= 1) {
        int a = (t >= o) ? s[t - o] : 0;
        __syncthreads();
        s[t] += a;
        __syncthreads();
    }
    if (i < L) base[i] = bsum[blockIdx.x] + s[t] - v;
}

// ---------- place edges into concatenated CSR; cursor IS base
__global__ void k_place(const int* __restrict__ row, const int* __restrict__ col,
                        int* __restrict__ base, int* __restrict__ pay, int F, int E) {
    int i = blockIdx.x * 256 + threadIdx.x;
    if (i >= E / 4) return;
    int4 r4 = reinterpret_cast<const int4*>(row)[i];
    int4 c4 = reinterpret_cast<const int4*>(col)[i];
#define PL(r, c) { \
    int pc = atomicAdd(&base[c], 1); pay[pc] = r; \
    int pr = atomicAdd(&base[F + r], 1); pay[pr] = c; }
    PL(r4.x, c4.x) PL(r4.y, c4.y) PL(r4.z, c4.z) PL(r4.w, c4.w)
#undef PL
}

// ---------- fragment pool (bf16 xb gather) + packed-f32 matvec; writes bf16 femb
__global__ __launch_bounds__(256) void k_frag(
        const unsigned short* __restrict__ xb, const int* __restrict__ base,
        const int* __restrict__ pay, const int* __restrict__ frag_id,
        const float* __restrict__ W_s, const float* __restrict__ E2,
        const float* __restrict__ bfs, unsigned short* __restrict__ fembb, int F, int E) {
    __shared__ f2 sI[FB / 2][HDIM];   // fragment PAIRS interleaved: sI[f>>1][k] = {f2f, f2f+1}
    __shared__ int eidx[TILE];
    __shared__ int cb[FB + 1];
    int t = threadIdx.x;
    int g = t >> 5, l = t & 31;
    int fb = blockIdx.x * FB;
    if (t <= FB) {
        int idx = fb + t - 1;
        cb[t] = (idx < 0) ? 0 : ((idx < F) ? base[idx] : E);
    }
    __syncthreads();
    int fr[4], st[4], dg[4];
#pragma unroll
    for (int q = 0; q < 4; ++q) {
        fr[q] = q * 8 + g;
        st[q] = cb[fr[q]];
        dg[q] = cb[fr[q] + 1] - st[q];
    }
    int p0 = cb[0], pend = cb[FB];
    const uint2* x2 = reinterpret_cast<const uint2*>(xb);
    float4 aA[4], aB[4];
#pragma unroll
    for (int q = 0; q < 4; ++q) {
        aA[q] = make_float4(0.f, 0.f, 0.f, 0.f);
        aB[q] = aA[q];
    }
    for (int tb = p0; tb < pend; tb += TILE) {
        int nload = min(TILE, pend - tb);
        for (int i = t; i < nload; i += 256) eidx[i] = pay[tb + i];
        __syncthreads();
        int lim = tb + nload;
        int lo[4], hi[4], m = 0;
#pragma unroll
        for (int q = 0; q < 4; ++q) {
            lo[q] = max(st[q], tb) - tb;
            hi[q] = min(st[q] + dg[q], lim) - tb;
            m = max(m, hi[q] - lo[q]);
        }
        for (int j = 0; j < m; j += 2) {
#pragma unroll
            for (int q = 0; q < 4; ++q) {
                if (lo[q] + j < hi[q])     { uint2 h = x2[(size_t)eidx[lo[q] + j]     * 32 + l]; ACCB(aA[q], h); }
                if (lo[q] + j + 1 < hi[q]) { uint2 h = x2[(size_t)eidx[lo[q] + j + 1] * 32 + l]; ACCB(aB[q], h); }
            }
        }
        __syncthreads();
    }
#pragma unroll
    for (int q = 0; q < 4; ++q) {
        float inv = 1.0f / fmaxf((float)dg[q], 1.0f);
        float4 r;
        r.x = (aA[q].x + aB[q].x) * inv; r.y = (aA[q].y + aB[q].y) * inv;
        r.z = (aA[q].z + aB[q].z) * inv; r.w = (aA[q].w + aB[q].w) * inv;
        int pr = fr[q] >> 1, pa = fr[q] & 1;
        if (pa == 0) {
            sI[pr][l * 4 + 0].x = r.x; sI[pr][l * 4 + 1].x = r.y;
            sI[pr][l * 4 + 2].x = r.z; sI[pr][l * 4 + 3].x = r.w;
        } else {
            sI[pr][l * 4 + 0].y = r.x; sI[pr][l * 4 + 1].y = r.y;
            sI[pr][l * 4 + 2].y = r.z; sI[pr][l * 4 + 3].y = r.w;
        }
    }
    __syncthreads();
    // matvec: thread = dim d; half fh handles 8 fragment-pairs (16 frags)
    int d = t & 127;
    int fh = t >> 7;
    float bv = bfs[d];
    f2 acc2[8];
#pragma unroll
    for (int q = 0; q < 8; ++q) {
        int pr = fh * 8 + q;
        int fA = fb + 2 * pr, fB = fA + 1;
        int idA = frag_id[min(fA, F - 1)];
        int idB = frag_id[min(fB, F - 1)];
        acc2[q].x = E2[(size_t)idA * HDIM + d] + bv;
        acc2[q].y = E2[(size_t)idB * HDIM + d] + bv;
    }
    for (int k = 0; k < HDIM; k += 2) {
        float w0 = W_s[(k + 0) * HDIM + d];
        float w1 = W_s[(k + 1) * HDIM + d];
        f2 w0v; w0v.x = w0; w0v.y = w0;
        f2 w1v; w1v.x = w1; w1v.y = w1;
#pragma unroll
        for (int q = 0; q < 8; ++q) {
            int pr = fh * 8 + q;
            f2 v0 = sI[pr][k];
            f2 v1 = sI[pr][k + 1];
            acc2[q] += v0 * w0v + v1 * w1v;
        }
    }
#pragma unroll
    for (int q = 0; q < 8; ++q) {
        int pr = fh * 8 + q;
        int fA = fb + 2 * pr;
        if (fA < F)     fembb[(size_t)fA * HDIM + d]       = f2bf(acc2[q].x);
        if (fA + 1 < F) fembb[(size_t)(fA + 1) * HDIM + d] = f2bf(acc2[q].y);
    }
}

// ---------- node pool + divide; bf16 femb gather, nt out stores
__global__ __launch_bounds__(256) void k_node(
        const unsigned short* __restrict__ fembb, const int* __restrict__ base,
        const int* __restrict__ pay, float* __restrict__ out, int F, int E, int N) {
    __shared__ int eidx[TILE_N];
    __shared__ int cb[NB + 1];
    int t = threadIdx.x;
    int g = t >> 5, l = t & 31;
    int n0 = blockIdx.x * NB;
    if (t <= NB) {
        int idx = n0 + t - 1;
        cb[t] = (idx < 0) ? E : base[F + idx];   // row region starts at E in pay
    }
    __syncthreads();
    int st_[8], dg_[8];
    float4 a[8];
#pragma unroll
    for (int i = 0; i < 8; ++i) {
        st_[i] = cb[g * 8 + i];
        dg_[i] = cb[g * 8 + i + 1] - st_[i];
        a[i] = make_float4(0.f, 0.f, 0.f, 0.f);
    }
    int p0 = cb[0], pend = cb[NB];
    const uint2* f2p = reinterpret_cast<const uint2*>(fembb);
    for (int tb = p0; tb < pend; tb += TILE_N) {
        int nload = min(TILE_N, pend - tb);
        for (int i = t; i < nload; i += 256) eidx[i] = pay[tb + i];
        __syncthreads();
        int lim = tb + nload;
        int lo[8], hi[8];
        int m = 0;
#pragma unroll
        for (int i = 0; i < 8; ++i) {
            lo[i] = max(st_[i], tb) - tb;
            hi[i] = min(st_[i] + dg_[i], lim) - tb;
            m = max(m, hi[i] - lo[i]);
        }
        for (int j = 0; j < m; ++j) {
#pragma unroll
            for (int i = 0; i < 8; ++i) {
                if (lo[i] + j < hi[i]) {
                    uint2 h = f2p[(size_t)eidx[lo[i] + j] * 32 + l];
                    ACCB(a[i], h);
                }
            }
        }
        __syncthreads();
    }
    f4* o4 = reinterpret_cast<f4*>(out);
#pragma unroll
    for (int i = 0; i < 8; ++i) {
        float inv = 1.0f / fmaxf((float)dg_[i], 1.0f);
        f4 v;
        v.x = a[i].x * inv; v.y = a[i].y * inv;
        v.z = a[i].z * inv; v.w = a[i].w * inv;
        __builtin_nontemporal_store(v, o4 + (size_t)(n0 + g * 8 + i) * 32 + l);
    }
}

extern "C" void kernel_launch(void* const* d_in, const int* in_sizes, int n_in,
                              void* d_out, int out_size, void* d_ws, size_t ws_size,
                              hipStream_t stream) {
    const float* x         = (const float*)d_in[0];
    const float* fragments = (const float*)d_in[1];
    const float* emb_table = (const float*)d_in[2];
    const float* W_f       = (const float*)d_in[3];
    const float* b_f       = (const float*)d_in[4];
    const float* W_s       = (const float*)d_in[5];
    const float* b_s       = (const float*)d_in[6];
    const int*   row       = (const int*)d_in[7];
    const int*   col       = (const int*)d_in[8];
    float* out = (float*)d_out;

    const int N = 200000, F = 50000, E = 400000;
    const int L = F + N;                 // concatenated CSR domain
    const int NBT = (L + 255) / 256;     // 977

    // xb (bf16 x, 51.2 MB) lives in d_out: fully dead before k_node overwrites out.
    unsigned short* xb = (unsigned short*)d_out;

    unsigned short* fembb = (unsigned short*)d_ws;     // F*128 bf16 = 12.8 MB
    int* cnt     = (int*)(fembb + (size_t)F * HDIM);   // L   (cols at 0, rows at F)
    int* base    = cnt + L;                            // L
    int* bsum    = base + L;                           // 1024
    int* pay     = bsum + 1024;                        // 2E  (col CSR at 0, row CSR at E)
    int* frag_id = pay + 2 * E;                        // F
    float* E2    = (float*)(frag_id + F);              // VOCAB*128
    float* bfs   = E2 + VOCAB * HDIM;                  // 128

    hipMemsetAsync(cnt, 0, (size_t)L * sizeof(int), stream);

    k_amc<<<25792, 256, 0, stream>>>(fragments, frag_id, x, xb, row, col, cnt,
                                     emb_table, W_f, W_s, b_f, b_s, E2, bfs, F);
    k_bsum<<<NBT, 256, 0, stream>>>(cnt, L, bsum);
    k_scan<<<1, 1024, 0, stream>>>(bsum, NBT);
    k_base<<<NBT, 256, 0, stream>>>(cnt, bsum, L, base);
    k_place<<<(E / 4 + 255) / 256, 256, 0, stream>>>(row, col, base, pay, F, E);
    k_frag<<<(F + FB - 1) / FB, 256, 0, stream>>>(xb, base, pay, frag_id, W_s, E2, bfs,
                                                  fembb, F, E);
    k_node<<<N / NB, 256, 0, stream>>>(fembb, base, pay, out, F, E, N);
}

// Round 9
// 241.761 us; speedup vs baseline: 1.5808x; 1.0344x over previous
//
#include <hip/hip_runtime.h>

#define HDIM 128
#define VOCAB 800
#define FB 32
#define NB 64
#define TILE 1024
#define TILE_N 512

typedef float f4 __attribute__((ext_vector_type(4)));
typedef float f2 __attribute__((ext_vector_type(2)));

// accumulate 8 bf16 (uint4 h) into two float4s
#define ACC8(pa, pb, h) { \
    pa.x += __uint_as_float(h.x << 16); \
    pa.y += __uint_as_float(h.x & 0xffff0000u); \
    pa.z += __uint_as_float(h.y << 16); \
    pa.w += __uint_as_float(h.y & 0xffff0000u); \
    pb.x += __uint_as_float(h.z << 16); \
    pb.y += __uint_as_float(h.z & 0xffff0000u); \
    pb.z += __uint_as_float(h.w << 16); \
    pb.w += __uint_as_float(h.w & 0xffff0000u); }

static __device__ __forceinline__ unsigned short f2bf(float f) {
    unsigned int u = __float_as_uint(f);
    return (unsigned short)((u + 0x7fffu + ((u >> 16) & 1u)) >> 16);
}

// ---------- mega streaming kernel:
// [0,12500)       argmax(fragments) via nt loads
// [12500,12891)   edge degree counts into concatenated cnt[] (cols at 0, rows at F)
// [12891,25391)   x -> bf16 xb (nt loads)
// [25391,25792)   E2 = (emb @ W_f) @ W_s_bot ; bfs = b_f @ W_s_bot + b_s
__global__ void k_amc(const float* __restrict__ frags, int* __restrict__ frag_id,
                      const float* __restrict__ x, unsigned short* __restrict__ xb,
                      const int* __restrict__ row, const int* __restrict__ col,
                      int* __restrict__ cnt,
                      const float* __restrict__ emb, const float* __restrict__ W_f,
                      const float* __restrict__ W_s, const float* __restrict__ b_f,
                      const float* __restrict__ b_s, float* __restrict__ E2,
                      float* __restrict__ bfs, int F) {
    __shared__ float e[2][HDIM], t1[2][HDIM];
    int b = blockIdx.x, t = threadIdx.x;
    if (b < 12500) {
        int wave = b * 4 + (t >> 6);
        int lane = t & 63;
        const f4* r = reinterpret_cast<const f4*>(frags + (size_t)wave * VOCAB);
        float best = -1e30f;
        int bidx = 0;
        for (int i = lane; i < VOCAB / 4; i += 64) {
            f4 v = __builtin_nontemporal_load(r + i);
            int base = i * 4;
            if (v.x > best) { best = v.x; bidx = base + 0; }
            if (v.y > best) { best = v.y; bidx = base + 1; }
            if (v.z > best) { best = v.z; bidx = base + 2; }
            if (v.w > best) { best = v.w; bidx = base + 3; }
        }
        for (int off = 32; off > 0; off >>= 1) {
            float ov = __shfl_xor(best, off, 64);
            int   oi = __shfl_xor(bidx, off, 64);
            if (ov > best || (ov == best && oi < bidx)) { best = ov; bidx = oi; }
        }
        if (lane == 0) frag_id[wave] = bidx;
    } else if (b < 12891) {
        int i = (b - 12500) * 256 + t;  // over E/4 = 100000 int4s
        if (i < 100000) {
            int4 r4 = reinterpret_cast<const int4*>(row)[i];
            int4 c4 = reinterpret_cast<const int4*>(col)[i];
            atomicAdd(&cnt[F + r4.x], 1); atomicAdd(&cnt[F + r4.y], 1);
            atomicAdd(&cnt[F + r4.z], 1); atomicAdd(&cnt[F + r4.w], 1);
            atomicAdd(&cnt[c4.x], 1); atomicAdd(&cnt[c4.y], 1);
            atomicAdd(&cnt[c4.z], 1); atomicAdd(&cnt[c4.w], 1);
        }
    } else if (b < 25391) {
        size_t i = (size_t)(b - 12891) * 256 + t;
        const f4* xp = reinterpret_cast<const f4*>(x);
        f4 v0 = __builtin_nontemporal_load(xp + 2 * i);
        f4 v1 = __builtin_nontemporal_load(xp + 2 * i + 1);
        uint4 o;
        o.x = (unsigned)f2bf(v0.x) | ((unsigned)f2bf(v0.y) << 16);
        o.y = (unsigned)f2bf(v0.z) | ((unsigned)f2bf(v0.w) << 16);
        o.z = (unsigned)f2bf(v1.x) | ((unsigned)f2bf(v1.y) << 16);
        o.w = (unsigned)f2bf(v1.z) | ((unsigned)f2bf(v1.w) << 16);
        *reinterpret_cast<uint4*>(xb + i * 8) = o;
    } else {
        int bp = b - 25391;         // 0..400
        int j = t & 127, half = t >> 7;
        if (bp < 400) {
            int v = bp * 2 + half;
            e[half][j] = emb[(size_t)v * HDIM + j];
            __syncthreads();
            float a = 0.f;
            for (int k = 0; k < HDIM; ++k)
                a = fmaf(e[half][k], W_f[k * HDIM + j], a);
            t1[half][j] = a;
            __syncthreads();
            float bb = 0.f;
            for (int k = 0; k < HDIM; ++k)
                bb = fmaf(t1[half][k], W_s[(HDIM + k) * HDIM + j], bb);
            E2[(size_t)v * HDIM + j] = bb;
        } else {
            if (half == 0) e[0][j] = b_f[j];
            __syncthreads();
            if (half == 0) {
                float bb = b_s[j];
                for (int k = 0; k < HDIM; ++k)
                    bb = fmaf(e[0][k], W_s[(HDIM + k) * HDIM + j], bb);
                bfs[j] = bb;
            }
        }
    }
}

// ---------- per-256-block sums over concatenated cnt (L = F+N)
__global__ void k_bsum(const int* __restrict__ cnt, int L, int* __restrict__ bsum) {
    __shared__ int s[256];
    int t = threadIdx.x;
    int i = blockIdx.x * 256 + t;
    s[t] = (i < L) ? cnt[i] : 0;
    __syncthreads();
    for (int o = 128; o > 0; o >>= 1) {
        if (t < o) s[t] += s[t + o];
        __syncthreads();
    }
    if (t == 0) bsum[blockIdx.x] = s[0];
}

// ---------- exclusive scan of block sums (nb <= 1024), single block
__global__ void k_scan(int* __restrict__ bsum, int nb) {
    __shared__ int s[1024];
    int t = threadIdx.x;
    int v = (t < nb) ? bsum[t] : 0;
    s[t] = v;
    __syncthreads();
    for (int o = 1; o < 1024; o <<= 1) {
        int a = (t >= o) ? s[t - o] : 0;
        __syncthreads();
        s[t] += a;
        __syncthreads();
    }
    if (t < nb) bsum[t] = s[t] - v;
}

// ---------- base[i] = bsum[block] + in-block exclusive scan
__global__ void k_base(const int* __restrict__ cnt, const int* __restrict__ bsum, int L,
                       int* __restrict__ base) {
    __shared__ int s[256];
    int t = threadIdx.x;
    int i = blockIdx.x * 256 + t;
    int v = (i < L) ? cnt[i] : 0;
    s[t] = v;
    __syncthreads();
    for (int o = 1; o < 256; o <<= 1) {
        int a = (t >= o) ? s[t - o] : 0;
        __syncthreads();
        s[t] += a;
        __syncthreads();
    }
    if (i < L) base[i] = bsum[blockIdx.x] + s[t] - v;
}

// ---------- place edges into concatenated CSR; cursor IS base
__global__ void k_place(const int* __restrict__ row, const int* __restrict__ col,
                        int* __restrict__ base, int* __restrict__ pay, int F, int E) {
    int i = blockIdx.x * 256 + threadIdx.x;
    if (i >= E / 4) return;
    int4 r4 = reinterpret_cast<const int4*>(row)[i];
    int4 c4 = reinterpret_cast<const int4*>(col)[i];
#define PL(r, c) { \
    int pc = atomicAdd(&base[c], 1); pay[pc] = r; \
    int pr = atomicAdd(&base[F + r], 1); pay[pr] = c; }
    PL(r4.x, c4.x) PL(r4.y, c4.y) PL(r4.z, c4.z) PL(r4.w, c4.w)
#undef PL
}

// ---------- fragment pool (bf16 xb gather, uint4/16-lane rows) + packed-f32 matvec
__global__ __launch_bounds__(256) void k_frag(
        const unsigned short* __restrict__ xb, const int* __restrict__ base,
        const int* __restrict__ pay, const int* __restrict__ frag_id,
        const float* __restrict__ W_s, const float* __restrict__ E2,
        const float* __restrict__ bfs, unsigned short* __restrict__ fembb, int F, int E) {
    __shared__ f2 sI[FB / 2][HDIM];   // fragment PAIRS interleaved
    __shared__ int eidx[TILE];
    __shared__ int cb[FB + 1];
    int t = threadIdx.x;
    int sg = t >> 4, l = t & 15;      // 16 sub-groups x 16 lanes; lane covers dims 8l..8l+7
    int fb = blockIdx.x * FB;
    if (t <= FB) {
        int idx = fb + t - 1;
        cb[t] = (idx < 0) ? 0 : ((idx < F) ? base[idx] : E);
    }
    __syncthreads();
    int st0 = cb[sg],      d0 = cb[sg + 1] - st0;
    int st1 = cb[16 + sg], d1 = cb[17 + sg] - st1;
    int p0 = cb[0], pend = cb[FB];
    const uint4* x4 = reinterpret_cast<const uint4*>(xb);   // row = 16 uint4
    float4 z = make_float4(0.f, 0.f, 0.f, 0.f);
    float4 a0A0 = z, a0A1 = z, a0B0 = z, a0B1 = z;
    float4 a1A0 = z, a1A1 = z, a1B0 = z, a1B1 = z;
    for (int tb = p0; tb < pend; tb += TILE) {
        int nload = min(TILE, pend - tb);
        for (int i = t; i < nload; i += 256) eidx[i] = pay[tb + i];
        __syncthreads();
        int lim = tb + nload;
        int lo0 = max(st0, tb) - tb, hi0 = min(st0 + d0, lim) - tb;
        int lo1 = max(st1, tb) - tb, hi1 = min(st1 + d1, lim) - tb;
        int m = max(hi0 - lo0, hi1 - lo1);
        for (int j = 0; j < m; j += 2) {
            if (lo0 + j < hi0)     { uint4 h = x4[(size_t)eidx[lo0 + j]     * 16 + l]; ACC8(a0A0, a0A1, h); }
            if (lo0 + j + 1 < hi0) { uint4 h = x4[(size_t)eidx[lo0 + j + 1] * 16 + l]; ACC8(a0B0, a0B1, h); }
            if (lo1 + j < hi1)     { uint4 h = x4[(size_t)eidx[lo1 + j]     * 16 + l]; ACC8(a1A0, a1A1, h); }
            if (lo1 + j + 1 < hi1) { uint4 h = x4[(size_t)eidx[lo1 + j + 1] * 16 + l]; ACC8(a1B0, a1B1, h); }
        }
        __syncthreads();
    }
    {
        float inv0 = 1.0f / fmaxf((float)d0, 1.0f);
        float inv1 = 1.0f / fmaxf((float)d1, 1.0f);
        int pr0 = sg >> 1, pa0 = sg & 1;
        int pr1 = (16 + sg) >> 1, pa1 = sg & 1;
        float v0[8] = { (a0A0.x + a0B0.x) * inv0, (a0A0.y + a0B0.y) * inv0,
                        (a0A0.z + a0B0.z) * inv0, (a0A0.w + a0B0.w) * inv0,
                        (a0A1.x + a0B1.x) * inv0, (a0A1.y + a0B1.y) * inv0,
                        (a0A1.z + a0B1.z) * inv0, (a0A1.w + a0B1.w) * inv0 };
        float v1[8] = { (a1A0.x + a1B0.x) * inv1, (a1A0.y + a1B0.y) * inv1,
                        (a1A0.z + a1B0.z) * inv1, (a1A0.w + a1B0.w) * inv1,
                        (a1A1.x + a1B1.x) * inv1, (a1A1.y + a1B1.y) * inv1,
                        (a1A1.z + a1B1.z) * inv1, (a1A1.w + a1B1.w) * inv1 };
#pragma unroll
        for (int i = 0; i < 8; ++i) {
            ((float*)&sI[pr0][8 * l + i])[pa0] = v0[i];
            ((float*)&sI[pr1][8 * l + i])[pa1] = v1[i];
        }
    }
    __syncthreads();
    // matvec: thread = dim d; half fh handles 8 fragment-pairs (16 frags)
    int d = t & 127;
    int fh = t >> 7;
    float bv = bfs[d];
    f2 acc2[8];
#pragma unroll
    for (int q = 0; q < 8; ++q) {
        int pr = fh * 8 + q;
        int fA = fb + 2 * pr, fB = fA + 1;
        int idA = frag_id[min(fA, F - 1)];
        int idB = frag_id[min(fB, F - 1)];
        acc2[q].x = E2[(size_t)idA * HDIM + d] + bv;
        acc2[q].y = E2[(size_t)idB * HDIM + d] + bv;
    }
    for (int k = 0; k < HDIM; k += 2) {
        float w0 = W_s[(k + 0) * HDIM + d];
        float w1 = W_s[(k + 1) * HDIM + d];
        f2 w0v; w0v.x = w0; w0v.y = w0;
        f2 w1v; w1v.x = w1; w1v.y = w1;
#pragma unroll
        for (int q = 0; q < 8; ++q) {
            int pr = fh * 8 + q;
            f2 vv0 = sI[pr][k];
            f2 vv1 = sI[pr][k + 1];
            acc2[q] += vv0 * w0v + vv1 * w1v;
        }
    }
#pragma unroll
    for (int q = 0; q < 8; ++q) {
        int pr = fh * 8 + q;
        int fA = fb + 2 * pr;
        if (fA < F)     fembb[(size_t)fA * HDIM + d]       = f2bf(acc2[q].x);
        if (fA + 1 < F) fembb[(size_t)(fA + 1) * HDIM + d] = f2bf(acc2[q].y);
    }
}

// ---------- node pool + divide; bf16 femb gather (uint4/16-lane rows), nt out stores
__global__ __launch_bounds__(256) void k_node(
        const unsigned short* __restrict__ fembb, const int* __restrict__ base,
        const int* __restrict__ pay, float* __restrict__ out, int F, int E, int N) {
    __shared__ int eidx[TILE_N];
    __shared__ int cb[NB + 1];
    int t = threadIdx.x;
    int sg = t >> 4, l = t & 15;      // 16 sub-groups; lane covers dims 8l..8l+7
    int n0 = blockIdx.x * NB;
    if (t <= NB) {
        int idx = n0 + t - 1;
        cb[t] = (idx < 0) ? E : base[F + idx];   // row region starts at E in pay
    }
    __syncthreads();
    int st_[4], dg_[4];
    float4 z = make_float4(0.f, 0.f, 0.f, 0.f);
    float4 aA0[4] = {z, z, z, z}, aA1[4] = {z, z, z, z};
    float4 aB0[4] = {z, z, z, z}, aB1[4] = {z, z, z, z};
#pragma unroll
    for (int q = 0; q < 4; ++q) {
        st_[q] = cb[sg * 4 + q];
        dg_[q] = cb[sg * 4 + q + 1] - st_[q];
    }
    int p0 = cb[0], pend = cb[NB];
    const uint4* f4p = reinterpret_cast<const uint4*>(fembb);
    for (int tb = p0; tb < pend; tb += TILE_N) {
        int nload = min(TILE_N, pend - tb);
        for (int i = t; i < nload; i += 256) eidx[i] = pay[tb + i];
        __syncthreads();
        int lim = tb + nload;
        int lo[4], hi[4];
        int m = 0;
#pragma unroll
        for (int q = 0; q < 4; ++q) {
            lo[q] = max(st_[q], tb) - tb;
            hi[q] = min(st_[q] + dg_[q], lim) - tb;
            m = max(m, hi[q] - lo[q]);
        }
        for (int j = 0; j < m; j += 2) {
#pragma unroll
            for (int q = 0; q < 4; ++q) {
                if (lo[q] + j < hi[q])     { uint4 h = f4p[(size_t)eidx[lo[q] + j]     * 16 + l]; ACC8(aA0[q], aA1[q], h); }
                if (lo[q] + j + 1 < hi[q]) { uint4 h = f4p[(size_t)eidx[lo[q] + j + 1] * 16 + l]; ACC8(aB0[q], aB1[q], h); }
            }
        }
        __syncthreads();
    }
    f4* o4 = reinterpret_cast<f4*>(out);
#pragma unroll
    for (int q = 0; q < 4; ++q) {
        float inv = 1.0f / fmaxf((float)dg_[q], 1.0f);
        f4 w0, w1;
        w0.x = (aA0[q].x + aB0[q].x) * inv; w0.y = (aA0[q].y + aB0[q].y) * inv;
        w0.z = (aA0[q].z + aB0[q].z) * inv; w0.w = (aA0[q].w + aB0[q].w) * inv;
        w1.x = (aA1[q].x + aB1[q].x) * inv; w1.y = (aA1[q].y + aB1[q].y) * inv;
        w1.z = (aA1[q].z + aB1[q].z) * inv; w1.w = (aA1[q].w + aB1[q].w) * inv;
        size_t nrow = (size_t)(n0 + sg * 4 + q) * 32;
        __builtin_nontemporal_store(w0, o4 + nrow + 2 * l + 0);
        __builtin_nontemporal_store(w1, o4 + nrow + 2 * l + 1);
    }
}

extern "C" void kernel_launch(void* const* d_in, const int* in_sizes, int n_in,
                              void* d_out, int out_size, void* d_ws, size_t ws_size,
                              hipStream_t stream) {
    const float* x         = (const float*)d_in[0];
    const float* fragments = (const float*)d_in[1];
    const float* emb_table = (const float*)d_in[2];
    const float* W_f       = (const float*)d_in[3];
    const float* b_f       = (const float*)d_in[4];
    const float* W_s       = (const float*)d_in[5];
    const float* b_s       = (const float*)d_in[6];
    const int*   row       = (const int*)d_in[7];
    const int*   col       = (const int*)d_in[8];
    float* out = (float*)d_out;

    const int N = 200000, F = 50000, E = 400000;
    const int L = F + N;                 // concatenated CSR domain
    const int NBT = (L + 255) / 256;     // 977

    // xb (bf16 x, 51.2 MB) lives in d_out: fully dead before k_node overwrites out.
    unsigned short* xb = (unsigned short*)d_out;

    unsigned short* fembb = (unsigned short*)d_ws;     // F*128 bf16 = 12.8 MB
    int* cnt     = (int*)(fembb + (size_t)F * HDIM);   // L   (cols at 0, rows at F)
    int* base    = cnt + L;                            // L
    int* bsum    = base + L;                           // 1024
    int* pay     = bsum + 1024;                        // 2E  (col CSR at 0, row CSR at E)
    int* frag_id = pay + 2 * E;                        // F
    float* E2    = (float*)(frag_id + F);              // VOCAB*128
    float* bfs   = E2 + VOCAB * HDIM;                  // 128

    hipMemsetAsync(cnt, 0, (size_t)L * sizeof(int), stream);

    k_amc<<<25792, 256, 0, stream>>>(fragments, frag_id, x, xb, row, col, cnt,
                                     emb_table, W_f, W_s, b_f, b_s, E2, bfs, F);
    k_bsum<<<NBT, 256, 0, stream>>>(cnt, L, bsum);
    k_scan<<<1, 1024, 0, stream>>>(bsum, NBT);
    k_base<<<NBT, 256, 0, stream>>>(cnt, bsum, L, base);
    k_place<<<(E / 4 + 255) / 256, 256, 0, stream>>>(row, col, base, pay, F, E);
    k_frag<<<(F + FB - 1) / FB, 256, 0, stream>>>(xb, base, pay, frag_id, W_s, E2, bfs,
                                                  fembb, F, E);
    k_node<<<N / NB, 256, 0, stream>>>(fembb, base, pay, out, F, E, N);
}